// Round 1
// baseline (551.161 us; speedup 1.0000x reference)
//
#include <hip/hip_runtime.h>

// PointPillarScatter: scatter (B*P, C) pillar features into dense BEV canvas
// out[b][ch][y][x], zero elsewhere.
// B=8, C=64, NX=432, NY=496, NZ=1, P_PER=4096.

#define PPS_NX   432
#define PPS_NY   496
#define PPS_GRID (PPS_NX * PPS_NY)   // 214272 (nz==1)
#define PPS_C    64

// Grid-stride float4 zeroing of the whole output canvas (438.8 MB).
// 16 B/lane stores -> coalescing sweet spot; expect ~6 TB/s.
__global__ void pps_zero_out(float4* __restrict__ out, long long n4) {
    long long i = (long long)blockIdx.x * blockDim.x + threadIdx.x;
    const long long stride = (long long)gridDim.x * blockDim.x;
    const float4 z = make_float4(0.f, 0.f, 0.f, 0.f);
    for (; i < n4; i += stride) {
        out[i] = z;
    }
}

// One thread per (pillar, channel). A 64-lane wave covers exactly one pillar:
//  - pf read: 64 consecutive floats -> one coalesced 256 B transaction.
//  - coords read: all lanes load the same int4 -> cache broadcast.
//  - write: 64 floats strided by GRID (different channel planes) -> inherently
//    scattered, but only 8 MB logical traffic vs 438 MB zeroing.
__global__ void pps_scatter(const float* __restrict__ pf,
                            const int4* __restrict__ coords,
                            float* __restrict__ out, int P) {
    int t = blockIdx.x * blockDim.x + threadIdx.x;
    int p = t >> 6;           // pillar index
    if (p >= P) return;
    int ch = t & 63;          // channel index

    int4 c = coords[p];       // (batch, z, y, x)
    // flat in-plane index: z + y*NX + x  (z==0 since NZ==1)
    long long pos = (long long)c.x * (long long)(PPS_C * PPS_GRID)
                  + (long long)ch * PPS_GRID
                  + (long long)c.y + (long long)c.z * PPS_NX + (long long)c.w;
    out[pos] = pf[t];
}

extern "C" void kernel_launch(void* const* d_in, const int* in_sizes, int n_in,
                              void* d_out, int out_size, void* d_ws, size_t ws_size,
                              hipStream_t stream) {
    const float* pf     = (const float*)d_in[0];
    const int4*  coords = (const int4*)d_in[1];
    float*       out    = (float*)d_out;

    // 1) zero the canvas (out_size = B*C*NY*NX, divisible by 4)
    long long n4 = (long long)out_size / 4;
    pps_zero_out<<<2048, 256, 0, stream>>>((float4*)out, n4);

    // 2) scatter pillars (same stream -> ordered after zeroing)
    int P = in_sizes[0] / PPS_C;          // number of pillars (B*P_PER)
    int threads = P * PPS_C;
    int blocks = (threads + 255) / 256;
    pps_scatter<<<blocks, 256, 0, stream>>>(pf, coords, out, P);
}

// Round 2
// 438.771 us; speedup vs baseline: 1.2561x; 1.2561x over previous
//
#include <hip/hip_runtime.h>

// PointPillarScatter: scatter (B*P, C) pillar features into dense BEV canvas
// out[b][ch][y][x], zero elsewhere. B=8, C=64, NX=432, NY=496, NZ=1.
//
// Strategy: build an inverse map (pixel -> pillar index) in d_ws, then a single
// gather kernel writes the 438.8 MB canvas exactly once, fully coalesced.

#define PPS_NX   432
#define PPS_NY   496
#define PPS_GRID (PPS_NX * PPS_NY)   // 214272, divisible by 4
#define PPS_C    64
#define PPS_B    8
#define PPS_U    (PPS_GRID / 4)      // 53568 float4-units per plane

// ---- Kernel 1: init inverse map to -1 (6.86 MB) -------------------------
__global__ void pps_init_map(int4* __restrict__ map4, int n4) {
    int i = blockIdx.x * blockDim.x + threadIdx.x;
    if (i < n4) map4[i] = make_int4(-1, -1, -1, -1);
}

// ---- Kernel 2: scatter pillar indices into the map (32768 x 4 B) --------
__global__ void pps_scatter_idx(const int4* __restrict__ coords,
                                int* __restrict__ map, int P) {
    int p = blockIdx.x * blockDim.x + threadIdx.x;
    if (p >= P) return;
    int4 c = coords[p];   // (batch, z, y, x)
    int pos = c.y + c.z * PPS_NX + c.w;           // in-plane index
    map[c.x * PPS_GRID + pos] = p;
}

// ---- Kernel 3: gather + single coalesced write of the canvas ------------
// Thread <-> (b, u) where u indexes 4 consecutive g. Reads map int4 once,
// loops ch over 64 channels: each wave stores 64x16 B = 1 KB contiguous per
// iteration (fully coalesced). Occupied lanes gather pillar rows as float4
// (4 channels at a time; pf is 8 MB -> L2-resident).
__global__ void pps_gather(const float* __restrict__ pf,
                           const int* __restrict__ map,
                           float* __restrict__ out) {
    int t = blockIdx.x * blockDim.x + threadIdx.x;   // exact: 8*53568 = 1674*256
    int b = t / PPS_U;
    int u = t - b * PPS_U;

    int4 m = ((const int4*)(map + b * PPS_GRID))[u];
    float* ob = out + (long long)b * (PPS_C * (long long)PPS_GRID) + 4 * u;

    const float4 z4 = make_float4(0.f, 0.f, 0.f, 0.f);
    for (int ch0 = 0; ch0 < PPS_C; ch0 += 4) {
        float4 p0 = z4, p1 = z4, p2 = z4, p3 = z4;
        if (m.x >= 0) p0 = *(const float4*)(pf + (long long)m.x * PPS_C + ch0);
        if (m.y >= 0) p1 = *(const float4*)(pf + (long long)m.y * PPS_C + ch0);
        if (m.z >= 0) p2 = *(const float4*)(pf + (long long)m.z * PPS_C + ch0);
        if (m.w >= 0) p3 = *(const float4*)(pf + (long long)m.w * PPS_C + ch0);

        float* o0 = ob + (long long)(ch0 + 0) * PPS_GRID;
        float* o1 = ob + (long long)(ch0 + 1) * PPS_GRID;
        float* o2 = ob + (long long)(ch0 + 2) * PPS_GRID;
        float* o3 = ob + (long long)(ch0 + 3) * PPS_GRID;
        *(float4*)o0 = make_float4(p0.x, p1.x, p2.x, p3.x);
        *(float4*)o1 = make_float4(p0.y, p1.y, p2.y, p3.y);
        *(float4*)o2 = make_float4(p0.z, p1.z, p2.z, p3.z);
        *(float4*)o3 = make_float4(p0.w, p1.w, p2.w, p3.w);
    }
}

// ---- Fallback (ws too small): zero + direct scatter ---------------------
__global__ void pps_zero_out(float4* __restrict__ out, long long n4) {
    long long i = (long long)blockIdx.x * blockDim.x + threadIdx.x;
    const long long stride = (long long)gridDim.x * blockDim.x;
    const float4 z = make_float4(0.f, 0.f, 0.f, 0.f);
    for (; i < n4; i += stride) out[i] = z;
}
__global__ void pps_scatter_feat(const float* __restrict__ pf,
                                 const int4* __restrict__ coords,
                                 float* __restrict__ out, int P) {
    int t = blockIdx.x * blockDim.x + threadIdx.x;
    int p = t >> 6;
    if (p >= P) return;
    int ch = t & 63;
    int4 c = coords[p];
    long long pos = (long long)c.x * (long long)(PPS_C * PPS_GRID)
                  + (long long)ch * PPS_GRID
                  + (long long)(c.y + c.z * PPS_NX + c.w);
    out[pos] = pf[t];
}

extern "C" void kernel_launch(void* const* d_in, const int* in_sizes, int n_in,
                              void* d_out, int out_size, void* d_ws, size_t ws_size,
                              hipStream_t stream) {
    const float* pf     = (const float*)d_in[0];
    const int4*  coords = (const int4*)d_in[1];
    float*       out    = (float*)d_out;
    int P = in_sizes[0] / PPS_C;   // B * P_PER = 32768

    const size_t map_bytes = (size_t)PPS_B * PPS_GRID * sizeof(int);
    if (ws_size >= map_bytes) {
        int* map = (int*)d_ws;
        // 1) map = -1
        int n4 = PPS_B * PPS_U;                       // 428544 int4 entries
        pps_init_map<<<(n4 + 255) / 256, 256, 0, stream>>>((int4*)map, n4);
        // 2) scatter pillar indices
        pps_scatter_idx<<<(P + 255) / 256, 256, 0, stream>>>(coords, map, P);
        // 3) gather + single coalesced canvas write (exact grid, no tail)
        pps_gather<<<PPS_B * PPS_U / 256, 256, 0, stream>>>(pf, map, out);
    } else {
        long long n4 = (long long)out_size / 4;
        pps_zero_out<<<2048, 256, 0, stream>>>((float4*)out, n4);
        int threads = P * PPS_C;
        pps_scatter_feat<<<(threads + 255) / 256, 256, 0, stream>>>(pf, coords, out, P);
    }
}